// Round 1
// baseline (195.043 us; speedup 1.0000x reference)
//
#include <hip/hip_runtime.h>
#include <math.h>

#define BATCH   512
#define NROWS   256
#define NVECS   8
#define VSIZE   128
#define DIM     1024   // NVECS*VSIZE
#define NCOMBO  256

// ---------------------------------------------------------------------------
// Kernel 0: inverse sub-vector norms.
// One wave (64 lanes) per 128-float sub-vector. 512*8 query + 256*8 weight
// sub-vectors = 6144 waves = 1536 blocks of 256 threads.
// ---------------------------------------------------------------------------
__global__ __launch_bounds__(256) void norms_kernel(
    const float* __restrict__ query,
    const float* __restrict__ weight,
    float* __restrict__ inv_qn,    // [512*8]
    float* __restrict__ inv_wn) {  // [256*8]
  int wid  = (blockIdx.x * blockDim.x + threadIdx.x) >> 6;
  int lane = threadIdx.x & 63;
  const float* src;
  float* dst;
  if (wid < BATCH * NVECS) {
    src = query + (size_t)wid * VSIZE;
    dst = inv_qn + wid;
  } else {
    int w2 = wid - BATCH * NVECS;
    src = weight + (size_t)w2 * VSIZE;
    dst = inv_wn + w2;
  }
  float2 v = *(const float2*)(src + lane * 2);
  float ss = v.x * v.x + v.y * v.y;
  #pragma unroll
  for (int m = 32; m >= 1; m >>= 1) ss += __shfl_xor(ss, m, 64);
  if (lane == 0) {
    float n = fmaxf(sqrtf(ss), 1e-8f);
    *dst = 1.0f / n;
  }
}

// ---------------------------------------------------------------------------
// Kernel 1: cos-sim dots. C[b][r][n] = relu(dot_n(q_b, w_r) * iq * iw).
// Tile: 32 b x 16 r per block of 256 threads; grid = 16 x 16 = 256 blocks.
// Thread t: tb = t&31 (b), tr = t>>5 (r and r+8) -> 2 pairs x 8 segments.
// LDS transposed [k][row] with odd padding -> conflict-free reads & writes;
// B reads are half-wave-uniform (broadcast, free).
// ---------------------------------------------------------------------------
__global__ __launch_bounds__(256) void dots_kernel(
    const float* __restrict__ q, const float* __restrict__ w,
    const float* __restrict__ inv_qn, const float* __restrict__ inv_wn,
    float* __restrict__ cs_out) {  // [512][256][8]
  __shared__ float As[64][33];   // [k][b], stride 33: bank = (k+b)&31
  __shared__ float Bs[64][17];   // [k][r], stride 17 (odd): conflict-free
  const int bs = blockIdx.x * 32;
  const int rs = blockIdx.y * 16;
  const int t  = threadIdx.x;
  const int tb = t & 31;
  const int tr = t >> 5;  // 0..7

  for (int n = 0; n < NVECS; ++n) {
    float s0 = 0.f, s1 = 0.f;
    for (int half = 0; half < 2; ++half) {
      const int k0 = n * VSIZE + half * 64;
      __syncthreads();  // protect LDS from previous chunk's readers
      #pragma unroll
      for (int i = 0; i < 8; ++i) {           // 32x64 A tile, coalesced
        int e = i * 256 + t;
        int kk = e & 63, bb = e >> 6;
        As[kk][bb] = q[(size_t)(bs + bb) * DIM + k0 + kk];
      }
      #pragma unroll
      for (int i = 0; i < 4; ++i) {           // 16x64 B tile, coalesced
        int e = i * 256 + t;
        int kk = e & 63, rr = e >> 6;
        Bs[kk][rr] = w[(size_t)(rs + rr) * DIM + k0 + kk];
      }
      __syncthreads();
      #pragma unroll
      for (int kk = 0; kk < 64; ++kk) {
        float a = As[kk][tb];
        s0 = fmaf(a, Bs[kk][tr], s0);
        s1 = fmaf(a, Bs[kk][tr + 8], s1);
      }
    }
    const float iq = inv_qn[(bs + tb) * NVECS + n];
    float c0 = s0 * iq * inv_wn[(rs + tr) * NVECS + n];
    float c1 = s1 * iq * inv_wn[(rs + tr + 8) * NVECS + n];
    cs_out[((size_t)(bs + tb) * NROWS + rs + tr) * NVECS + n]     = fmaxf(c0, 0.f);
    cs_out[((size_t)(bs + tb) * NROWS + rs + tr + 8) * NVECS + n] = fmaxf(c1, 0.f);
  }
}

// ---------------------------------------------------------------------------
// Kernel 2: combo expansion. One wave per (b,r) pair-iteration.
// Lane l writes combos c = 4l..4l+3 as one float4 (coalesced 1 KB/wave).
// combo bit j of c: 0 -> cs[j], 1 -> 1-cs[j]. Bits 2..7 come from l,
// bits 0..1 from the float4 component -> factor the product:
// base = prod(bits 2..7 terms), then x {cs0*cs1, (1-cs0)*cs1, ...}.
// ---------------------------------------------------------------------------
#define PAIRS_PER_WAVE 16
__global__ __launch_bounds__(256) void expand_kernel(
    const float* __restrict__ cs, float* __restrict__ out) {
  const int lane = threadIdx.x & 63;
  const int wid  = blockIdx.x * (blockDim.x >> 6) + (threadIdx.x >> 6);
  const size_t p0 = (size_t)wid * PAIRS_PER_WAVE;
  for (int i = 0; i < PAIRS_PER_WAVE; ++i) {
    const size_t pair = p0 + i;
    const float4* cp = (const float4*)(cs + pair * NVECS);
    float4 cA = cp[0];  // cs0..cs3
    float4 cB = cp[1];  // cs4..cs7
    float t2 = (lane & 1)  ? 1.f - cA.z : cA.z;
    float t3 = (lane & 2)  ? 1.f - cA.w : cA.w;
    float t4 = (lane & 4)  ? 1.f - cB.x : cB.x;
    float t5 = (lane & 8)  ? 1.f - cB.y : cB.y;
    float t6 = (lane & 16) ? 1.f - cB.z : cB.z;
    float t7 = (lane & 32) ? 1.f - cB.w : cB.w;
    float base = ((t2 * t3) * (t4 * t5)) * (t6 * t7);
    float c0 = cA.x, c1 = cA.y;
    float m0 = c0 * c1;
    float m1 = (1.f - c0) * c1;
    float m2 = c0 * (1.f - c1);
    float m3 = (1.f - c0) * (1.f - c1);
    float4 o;
    o.x = base * m0;
    o.y = base * m1;
    o.z = base * m2;
    o.w = base * m3;
    *(float4*)(out + pair * NCOMBO + lane * 4) = o;
  }
}

// ---------------------------------------------------------------------------
extern "C" void kernel_launch(void* const* d_in, const int* in_sizes, int n_in,
                              void* d_out, int out_size, void* d_ws, size_t ws_size,
                              hipStream_t stream) {
  const float* query  = (const float*)d_in[0];   // [512][1024]
  const float* weight = (const float*)d_in[1];   // [256][1024]
  float* out = (float*)d_out;                    // [512][256][256]

  // workspace layout: cs (4 MB) | inv_qn (16 KB) | inv_wn (8 KB)
  float* cs     = (float*)d_ws;
  float* inv_qn = cs + (size_t)BATCH * NROWS * NVECS;
  float* inv_wn = inv_qn + BATCH * NVECS;

  // 6144 sub-vector norms, 4 waves/block -> 1536 blocks
  hipLaunchKernelGGL(norms_kernel, dim3(1536), dim3(256), 0, stream,
                     query, weight, inv_qn, inv_wn);
  // 16 x 16 tiles of 32b x 16r
  hipLaunchKernelGGL(dots_kernel, dim3(16, 16), dim3(256), 0, stream,
                     query, weight, inv_qn, inv_wn, cs);
  // 131072 pairs / 16 per wave = 8192 waves = 2048 blocks
  hipLaunchKernelGGL(expand_kernel, dim3(2048), dim3(256), 0, stream,
                     cs, out);
}

// Round 3
// 148.230 us; speedup vs baseline: 1.3158x; 1.3158x over previous
//
#include <hip/hip_runtime.h>
#include <math.h>

#define BATCH  512
#define NROWS  256
#define NVECS  8
#define VSIZE  128
#define DIM    1024   // NVECS*VSIZE
#define NCOMBO 256

typedef float vf4 __attribute__((ext_vector_type(4)));  // clang-native float4

// ---------------------------------------------------------------------------
// Kernel A: prescale each 128-float sub-vector to unit norm (max(norm,eps)).
// One wave per sub-vector; 512*8 + 256*8 = 6144 waves = 1536 blocks.
// After this, dot(q',w') IS the cosine similarity.
// ---------------------------------------------------------------------------
__global__ __launch_bounds__(256) void prescale_kernel(
    const float* __restrict__ q, const float* __restrict__ w,
    float* __restrict__ qn, float* __restrict__ wn) {
  int wid  = (blockIdx.x * 256 + threadIdx.x) >> 6;   // 0..6143
  int lane = threadIdx.x & 63;
  const float* src; float* dst;
  if (wid < BATCH * NVECS) {
    src = q  + (size_t)wid * VSIZE;
    dst = qn + (size_t)wid * VSIZE;
  } else {
    int k = wid - BATCH * NVECS;
    src = w  + (size_t)k * VSIZE;
    dst = wn + (size_t)k * VSIZE;
  }
  float2 v = *(const float2*)(src + lane * 2);
  float ss = fmaf(v.x, v.x, v.y * v.y);
  #pragma unroll
  for (int m = 1; m <= 32; m <<= 1) ss += __shfl_xor(ss, m, 64);
  float inv = 1.0f / fmaxf(sqrtf(ss), 1e-8f);
  float2 o; o.x = v.x * inv; o.y = v.y * inv;
  *(float2*)(dst + lane * 2) = o;
}

// ---------------------------------------------------------------------------
// Kernel B: fused dots + combo expansion. Tile = 8 b x 8 r = 64 pairs/block,
// 256 threads (4 waves), grid 64 x 32 = 2048 blocks (8/CU).
//
// Phase 1 (dots): wave wv owns b-rows {2wv, 2wv+1} x all 8 r.
//   Lane l = (n = l>>3, c = l&7) covers elements [n*128 + c*16, +16).
//   Q rows live in registers (32 VGPR, one global read, L2-hot).
//   W tile staged in LDS, padded +4 per 128-seg: strided b128 reads land
//   exactly 8 lanes per bank-group (the b128 conflict-free optimum).
//   Dot reduce = 3-step xor butterfly over c; lanes c<2 write cs to LDS.
// Phase 2 (expand): wave expands its own 16 pairs; lane l writes combos
//   4l..4l+3 as one nontemporal float4 (1 KB/wave coalesced). Write-bound.
// ---------------------------------------------------------------------------
__global__ __launch_bounds__(256) void fused_kernel(
    const float* __restrict__ q, const float* __restrict__ w,
    float* __restrict__ out) {
  __shared__ __align__(16) float Ws[8 * 1056];  // 8 rows, 8 segs x (128+4)
  __shared__ __align__(16) float CS[64][8];     // [pair_local][n]
  const int t  = threadIdx.x;
  const int wv = t >> 6, lane = t & 63;
  const int bs = blockIdx.x * 8, rs = blockIdx.y * 8;

  // stage W tile (8 x 1024 floats), coalesced float4 loads, padded LDS writes
  #pragma unroll
  for (int i = 0; i < 8; ++i) {
    int f = i * 256 + t;        // float4 index 0..2047
    int g = f << 2;             // element index
    int row = g >> 10, e = g & 1023;
    float4 v = *(const float4*)(w + (size_t)(rs + row) * DIM + e);
    *(float4*)(Ws + row * 1056 + (e >> 7) * 132 + (e & 127)) = v;
  }

  const int n = lane >> 3, c = lane & 7;
  const int koff = n * VSIZE + c * 16;

  float4 qa[4], qb[4];
  {
    const float* Q0 = q + (size_t)(bs + 2 * wv) * DIM + koff;
    #pragma unroll
    for (int j = 0; j < 4; ++j) {
      qa[j] = *(const float4*)(Q0 + 4 * j);
      qb[j] = *(const float4*)(Q0 + DIM + 4 * j);
    }
  }
  __syncthreads();

  const float* Wb = Ws + n * 132 + c * 16;
  #pragma unroll
  for (int r = 0; r < 8; ++r) {
    const float* Wr = Wb + r * 1056;
    float s0 = 0.f, s1 = 0.f;
    #pragma unroll
    for (int j = 0; j < 4; ++j) {
      float4 w4 = *(const float4*)(Wr + 4 * j);
      s0 = fmaf(qa[j].x, w4.x, s0); s0 = fmaf(qa[j].y, w4.y, s0);
      s0 = fmaf(qa[j].z, w4.z, s0); s0 = fmaf(qa[j].w, w4.w, s0);
      s1 = fmaf(qb[j].x, w4.x, s1); s1 = fmaf(qb[j].y, w4.y, s1);
      s1 = fmaf(qb[j].z, w4.z, s1); s1 = fmaf(qb[j].w, w4.w, s1);
    }
    #pragma unroll
    for (int m = 1; m <= 4; m <<= 1) {
      s0 += __shfl_xor(s0, m, 64);
      s1 += __shfl_xor(s1, m, 64);
    }
    if (c < 2) {
      float v = (c == 0) ? s0 : s1;
      CS[(2 * wv + c) * 8 + r][n] = fmaxf(v, 0.f);
    }
  }
  __syncthreads();

  // expand: wave expands pairs p = wv*16 .. wv*16+15 (the ones it computed)
  #pragma unroll 4
  for (int i = 0; i < 16; ++i) {
    int p = wv * 16 + i;
    int bl = p >> 3, r = p & 7;
    float4 cA = *(const float4*)(&CS[p][0]);
    float4 cB = *(const float4*)(&CS[p][4]);
    float t2 = (lane & 1)  ? 1.f - cA.z : cA.z;
    float t3 = (lane & 2)  ? 1.f - cA.w : cA.w;
    float t4 = (lane & 4)  ? 1.f - cB.x : cB.x;
    float t5 = (lane & 8)  ? 1.f - cB.y : cB.y;
    float t6 = (lane & 16) ? 1.f - cB.z : cB.z;
    float t7 = (lane & 32) ? 1.f - cB.w : cB.w;
    float base = ((t2 * t3) * (t4 * t5)) * (t6 * t7);
    float c0 = cA.x, c1 = cA.y;
    vf4 o;
    o.x = base * (c0 * c1);
    o.y = base * ((1.f - c0) * c1);
    o.z = base * (c0 * (1.f - c1));
    o.w = base * ((1.f - c0) * (1.f - c1));
    size_t off = ((size_t)(bs + bl) * NROWS + (rs + r)) * NCOMBO + lane * 4;
    __builtin_nontemporal_store(o, (vf4*)(out + off));
  }
}

// ---------------------------------------------------------------------------
extern "C" void kernel_launch(void* const* d_in, const int* in_sizes, int n_in,
                              void* d_out, int out_size, void* d_ws, size_t ws_size,
                              hipStream_t stream) {
  const float* query  = (const float*)d_in[0];   // [512][1024]
  const float* weight = (const float*)d_in[1];   // [256][1024]
  float* out = (float*)d_out;                    // [512][256][256]

  // ws: q' (2 MB) | w' (1 MB)
  float* qn = (float*)d_ws;
  float* wn = qn + (size_t)BATCH * DIM;

  hipLaunchKernelGGL(prescale_kernel, dim3(1536), dim3(256), 0, stream,
                     query, weight, qn, wn);
  hipLaunchKernelGGL(fused_kernel, dim3(64, 32), dim3(256), 0, stream,
                     qn, wn, out);
}

// Round 4
// 145.466 us; speedup vs baseline: 1.3408x; 1.0190x over previous
//
#include <hip/hip_runtime.h>
#include <math.h>

#define BATCH  512
#define NROWS  256
#define NVECS  8
#define VSIZE  128
#define DIM    1024   // NVECS*VSIZE
#define NCOMBO 256

typedef float vf4 __attribute__((ext_vector_type(4)));  // clang-native float4

// ---------------------------------------------------------------------------
// Single fused kernel: dots + inline norms + combo expansion.
// Tile = 8 b x 8 r = 64 pairs/block, 256 threads (4 waves),
// grid 64 x 32 = 2048 blocks (8/CU).
//
// Phase 1 (dots): wave wv owns b-rows {2wv, 2wv+1} x all 8 r.
//   Lane l = (n = l>>3, c = l&7) covers elements [n*128 + c*16, +16).
//   Q rows live in registers (raw, one global read, L2-hot).
//   Q sub-vector sumsq: butterfly over c before the r-loop.
//   W tile staged (raw) in LDS, padded +4 per 128-seg: strided b128 reads
//   land 8 lanes/bank-group (b128 conflict-free optimum).
//   Per r: accumulate dot0, dot1 and w-sumsq; reduce all three in one
//   3-step xor butterfly over c; cos = dot * invq * invw; relu; lanes c<2
//   stage cs into LDS.
// Phase 2 (expand): wave expands its own 16 pairs; lane l writes combos
//   4l..4l+3 as one cacheable float4 (1 KB/wave coalesced; L3 absorbs,
//   drain overlaps with subsequent work).
// ---------------------------------------------------------------------------
__global__ __launch_bounds__(256) void fused_kernel(
    const float* __restrict__ q, const float* __restrict__ w,
    float* __restrict__ out) {
  __shared__ __align__(16) float Ws[8 * 1056];  // 8 rows, 8 segs x (128+4)
  __shared__ __align__(16) float CS[64][8];     // [pair_local][n]
  const int t  = threadIdx.x;
  const int wv = t >> 6, lane = t & 63;
  const int bs = blockIdx.x * 8, rs = blockIdx.y * 8;

  // stage W tile (8 x 1024 floats), coalesced float4 loads, padded LDS writes
  #pragma unroll
  for (int i = 0; i < 8; ++i) {
    int f = i * 256 + t;        // float4 index 0..2047
    int g = f << 2;             // element index
    int row = g >> 10, e = g & 1023;
    float4 v = *(const float4*)(w + (size_t)(rs + row) * DIM + e);
    *(float4*)(Ws + row * 1056 + (e >> 7) * 132 + (e & 127)) = v;
  }

  const int n = lane >> 3, c = lane & 7;
  const int koff = n * VSIZE + c * 16;

  // Q rows -> registers; inline sub-vector inverse norms via butterfly.
  float4 qa[4], qb[4];
  float qs0 = 0.f, qs1 = 0.f;
  {
    const float* Q0 = q + (size_t)(bs + 2 * wv) * DIM + koff;
    #pragma unroll
    for (int j = 0; j < 4; ++j) {
      qa[j] = *(const float4*)(Q0 + 4 * j);
      qb[j] = *(const float4*)(Q0 + DIM + 4 * j);
      qs0 = fmaf(qa[j].x, qa[j].x, qs0); qs0 = fmaf(qa[j].y, qa[j].y, qs0);
      qs0 = fmaf(qa[j].z, qa[j].z, qs0); qs0 = fmaf(qa[j].w, qa[j].w, qs0);
      qs1 = fmaf(qb[j].x, qb[j].x, qs1); qs1 = fmaf(qb[j].y, qb[j].y, qs1);
      qs1 = fmaf(qb[j].z, qb[j].z, qs1); qs1 = fmaf(qb[j].w, qb[j].w, qs1);
    }
  }
  #pragma unroll
  for (int m = 1; m <= 4; m <<= 1) {
    qs0 += __shfl_xor(qs0, m, 64);
    qs1 += __shfl_xor(qs1, m, 64);
  }
  const float iq0 = 1.0f / fmaxf(sqrtf(qs0), 1e-8f);
  const float iq1 = 1.0f / fmaxf(sqrtf(qs1), 1e-8f);
  __syncthreads();

  const float* Wb = Ws + n * 132 + c * 16;
  #pragma unroll
  for (int r = 0; r < 8; ++r) {
    const float* Wr = Wb + r * 1056;
    float s0 = 0.f, s1 = 0.f, wss = 0.f;
    #pragma unroll
    for (int j = 0; j < 4; ++j) {
      float4 w4 = *(const float4*)(Wr + 4 * j);
      s0 = fmaf(qa[j].x, w4.x, s0); s0 = fmaf(qa[j].y, w4.y, s0);
      s0 = fmaf(qa[j].z, w4.z, s0); s0 = fmaf(qa[j].w, w4.w, s0);
      s1 = fmaf(qb[j].x, w4.x, s1); s1 = fmaf(qb[j].y, w4.y, s1);
      s1 = fmaf(qb[j].z, w4.z, s1); s1 = fmaf(qb[j].w, w4.w, s1);
      wss = fmaf(w4.x, w4.x, wss); wss = fmaf(w4.y, w4.y, wss);
      wss = fmaf(w4.z, w4.z, wss); wss = fmaf(w4.w, w4.w, wss);
    }
    #pragma unroll
    for (int m = 1; m <= 4; m <<= 1) {
      s0  += __shfl_xor(s0, m, 64);
      s1  += __shfl_xor(s1, m, 64);
      wss += __shfl_xor(wss, m, 64);
    }
    const float iw = 1.0f / fmaxf(sqrtf(wss), 1e-8f);
    if (c < 2) {
      float v = (c == 0) ? s0 * iq0 * iw : s1 * iq1 * iw;
      CS[(2 * wv + c) * 8 + r][n] = fmaxf(v, 0.f);
    }
  }
  __syncthreads();

  // expand: wave expands pairs p = wv*16 .. wv*16+15 (the ones it computed)
  #pragma unroll 4
  for (int i = 0; i < 16; ++i) {
    int p = wv * 16 + i;
    int bl = p >> 3, r = p & 7;
    float4 cA = *(const float4*)(&CS[p][0]);
    float4 cB = *(const float4*)(&CS[p][4]);
    float t2 = (lane & 1)  ? 1.f - cA.z : cA.z;
    float t3 = (lane & 2)  ? 1.f - cA.w : cA.w;
    float t4 = (lane & 4)  ? 1.f - cB.x : cB.x;
    float t5 = (lane & 8)  ? 1.f - cB.y : cB.y;
    float t6 = (lane & 16) ? 1.f - cB.z : cB.z;
    float t7 = (lane & 32) ? 1.f - cB.w : cB.w;
    float base = ((t2 * t3) * (t4 * t5)) * (t6 * t7);
    float c0 = cA.x, c1 = cA.y;
    float4 o;
    o.x = base * (c0 * c1);
    o.y = base * ((1.f - c0) * c1);
    o.z = base * (c0 * (1.f - c1));
    o.w = base * ((1.f - c0) * (1.f - c1));
    size_t off = ((size_t)(bs + bl) * NROWS + (rs + r)) * NCOMBO + lane * 4;
    *(float4*)(out + off) = o;   // cacheable: let L2/L3 absorb, drain later
  }
}

// ---------------------------------------------------------------------------
extern "C" void kernel_launch(void* const* d_in, const int* in_sizes, int n_in,
                              void* d_out, int out_size, void* d_ws, size_t ws_size,
                              hipStream_t stream) {
  const float* query  = (const float*)d_in[0];   // [512][1024]
  const float* weight = (const float*)d_in[1];   // [256][1024]
  float* out = (float*)d_out;                    // [512][256][256]
  (void)d_ws; (void)ws_size;

  hipLaunchKernelGGL(fused_kernel, dim3(64, 32), dim3(256), 0, stream,
                     query, weight, out);
}